// Round 2
// baseline (130.198 us; speedup 1.0000x reference)
//
#include <hip/hip_runtime.h>

// TemporalDenoise: bidirectional per-channel EMA, averaged.
// Chunked-with-halo parallel scan (carry decays as (1-a)^k; a=0.3 ->
// 0.7^24 ~ 1.9e-4, well under the 5e-2 threshold).
// R2: latency-bound fix. float4 across channels (4 ch/thread, 16B loads),
// LCH=16 so fwd[] = 64 VGPRs, __launch_bounds__(256,4) caps VGPR<=128
// -> 4 waves/SIMD. Nontemporal stores keep x L3-resident.

#define BB 32
#define TT 2048
#define CC 512
#define CG (CC / 4)      // 128 float4 channel-groups
#define LCH 16           // time steps per thread
#define HALO 24          // warm-up halo
#define NCH (TT / LCH)   // 128 chunks

typedef float f32x4 __attribute__((ext_vector_type(4)));

static __device__ __forceinline__ void ema4(f32x4& c, const f32x4 v,
                                            const f32x4 a, const f32x4 d) {
  c.x = fmaf(a.x, v.x, d.x * c.x);
  c.y = fmaf(a.y, v.y, d.y * c.y);
  c.z = fmaf(a.z, v.z, d.z * c.z);
  c.w = fmaf(a.w, v.w, d.w * c.w);
}

__global__ __launch_bounds__(256, 4) void ema_bidir_kernel(
    const f32x4* __restrict__ x, const f32x4* __restrict__ alogit4,
    f32x4* __restrict__ out) {
  const int g = blockIdx.x * blockDim.x + threadIdx.x;
  const int cg = g % CG;
  const int bc = g / CG;
  const int b = bc % BB;
  const int j = bc / BB;  // chunk index
  const int t0 = j * LCH;

  const f32x4 al = alogit4[cg];
  f32x4 a, d;
  a.x = 1.0f / (1.0f + __expf(-al.x));
  a.y = 1.0f / (1.0f + __expf(-al.y));
  a.z = 1.0f / (1.0f + __expf(-al.z));
  a.w = 1.0f / (1.0f + __expf(-al.w));
  d = 1.0f - a;

  const f32x4* xrow = x + (size_t)b * TT * CG + cg;
  f32x4* orow = out + (size_t)b * TT * CG + cg;

  // ---- forward warm-up ----
  int ts = t0 - HALO;
  if (ts < 0) ts = 0;
  f32x4 cf = xrow[(size_t)ts * CG];
  for (int t = ts + 1; t < t0; ++t) ema4(cf, xrow[(size_t)t * CG], a, d);

  // ---- backward warm-up ----
  int te = t0 + LCH - 1 + HALO;
  if (te > TT - 1) te = TT - 1;
  f32x4 cb = xrow[(size_t)te * CG];
  for (int t = te - 1; t >= t0 + LCH; --t) ema4(cb, xrow[(size_t)t * CG], a, d);

  // ---- forward main: record chunk in registers ----
  f32x4 f[LCH];
#pragma unroll
  for (int i = 0; i < LCH; ++i) {
    ema4(cf, xrow[(size_t)(t0 + i) * CG], a, d);
    f[i] = cf;  // at t0==0,i==0: a*x0 + d*x0 == x0 (matches ref init)
  }

  // ---- backward main, fused averaged nontemporal store ----
#pragma unroll
  for (int i = LCH - 1; i >= 0; --i) {
    ema4(cb, xrow[(size_t)(t0 + i) * CG], a, d);
    f32x4 r;
    r.x = 0.5f * (f[i].x + cb.x);
    r.y = 0.5f * (f[i].y + cb.y);
    r.z = 0.5f * (f[i].z + cb.z);
    r.w = 0.5f * (f[i].w + cb.w);
    __builtin_nontemporal_store(r, &orow[(size_t)(t0 + i) * CG]);
  }
}

extern "C" void kernel_launch(void* const* d_in, const int* in_sizes, int n_in,
                              void* d_out, int out_size, void* d_ws,
                              size_t ws_size, hipStream_t stream) {
  const f32x4* x = (const f32x4*)d_in[0];
  const f32x4* alogit4 = (const f32x4*)d_in[1];
  f32x4* out = (f32x4*)d_out;

  const int total = BB * CG * NCH;  // 524288 threads
  const int block = 256;
  const int grid = total / block;   // 2048 blocks
  ema_bidir_kernel<<<grid, block, 0, stream>>>(x, alogit4, out);
}

// Round 3
// 115.063 us; speedup vs baseline: 1.1315x; 1.1315x over previous
//
#include <hip/hip_runtime.h>

// TemporalDenoise: bidirectional per-channel EMA, averaged.
// R3: single-owner-per-cacheline tiling. Each block owns (b, 128B channel
// slice = 8 f32x4 groups, 512 time steps). Threads = 8 cg x 32 time-chunks
// of LCH=16 with HALO=32 warm-up (0.7^32 ~ 1e-5 << 5e-2 threshold).
// All halo amplification (6x logical reads) stays inside the block's 64KB
// working set -> own-XCD L2 hits; L2-miss traffic ~= compulsory 128MB+132MB.
// Clamped-index warm-up makes t=0 / t=T-1 boundaries exact (carry converges
// to x[0] / x[T-1], matching the reference init).

#define BB 32
#define TT 2048
#define CC 512
#define CG 128          // f32x4 groups per (b,t) row
#define CGT 8           // f32x4 groups per block = 128B = one cacheline
#define NCGT (CG / CGT) // 16
#define LCH 16          // time steps per thread
#define NCHB 32         // chunks per block (256 threads / 8 cg)
#define TB (LCH * NCHB) // 512 time steps per block
#define NTB (TT / TB)   // 4
#define HALO 32

typedef float f32x4 __attribute__((ext_vector_type(4)));

static __device__ __forceinline__ void ema4(f32x4& c, const f32x4 v,
                                            const f32x4 a, const f32x4 d) {
  c.x = fmaf(a.x, v.x, d.x * c.x);
  c.y = fmaf(a.y, v.y, d.y * c.y);
  c.z = fmaf(a.z, v.z, d.z * c.z);
  c.w = fmaf(a.w, v.w, d.w * c.w);
}

__global__ __launch_bounds__(256, 4) void ema_bidir_kernel(
    const f32x4* __restrict__ x, const f32x4* __restrict__ alogit4,
    f32x4* __restrict__ out) {
  const int bid = blockIdx.x;
  const int tb = bid & (NTB - 1);          // time tile
  const int cgt = (bid >> 2) & (NCGT - 1); // channel tile
  const int b = bid >> 6;                  // batch

  const int tid = threadIdx.x;
  const int cgi = tid & (CGT - 1); // 0..7  channel group within tile
  const int ch = tid >> 3;         // 0..31 chunk within tile

  const int cg = cgt * CGT + cgi;
  const int t0 = tb * TB + ch * LCH;

  const f32x4 al = alogit4[cg];
  f32x4 a, d;
  a.x = 1.0f / (1.0f + __expf(-al.x));
  a.y = 1.0f / (1.0f + __expf(-al.y));
  a.z = 1.0f / (1.0f + __expf(-al.z));
  a.w = 1.0f / (1.0f + __expf(-al.w));
  d = 1.0f - a;

  const f32x4* xrow = x + (size_t)b * TT * CG + cg;
  f32x4* orow = out + (size_t)b * TT * CG + cg;

  // ---- forward warm-up (clamped indices; exact at t0==0) ----
  const int ts0 = t0 - HALO;
  f32x4 cf = xrow[(size_t)(ts0 < 0 ? 0 : ts0) * CG];
#pragma unroll
  for (int k = 1; k < HALO; ++k) {
    int t = ts0 + k;
    if (t < 0) t = 0;
    ema4(cf, xrow[(size_t)t * CG], a, d);
  }

  // ---- backward warm-up (clamped; exact at t0+LCH==TT) ----
  const int te0 = t0 + LCH - 1 + HALO;
  f32x4 cb = xrow[(size_t)(te0 > TT - 1 ? TT - 1 : te0) * CG];
#pragma unroll
  for (int k = 1; k < HALO; ++k) {
    int t = te0 - k;
    if (t > TT - 1) t = TT - 1;
    ema4(cb, xrow[(size_t)t * CG], a, d);
  }

  // ---- forward main: record chunk in registers ----
  f32x4 f[LCH];
#pragma unroll
  for (int i = 0; i < LCH; ++i) {
    ema4(cf, xrow[(size_t)(t0 + i) * CG], a, d);
    f[i] = cf;
  }

  // ---- backward main (re-reads are block-local L2 hits), fused store ----
#pragma unroll
  for (int i = LCH - 1; i >= 0; --i) {
    ema4(cb, xrow[(size_t)(t0 + i) * CG], a, d);
    f32x4 r;
    r.x = 0.5f * (f[i].x + cb.x);
    r.y = 0.5f * (f[i].y + cb.y);
    r.z = 0.5f * (f[i].z + cb.z);
    r.w = 0.5f * (f[i].w + cb.w);
    __builtin_nontemporal_store(r, &orow[(size_t)(t0 + i) * CG]);
  }
}

extern "C" void kernel_launch(void* const* d_in, const int* in_sizes, int n_in,
                              void* d_out, int out_size, void* d_ws,
                              size_t ws_size, hipStream_t stream) {
  const f32x4* x = (const f32x4*)d_in[0];
  const f32x4* alogit4 = (const f32x4*)d_in[1];
  f32x4* out = (f32x4*)d_out;

  const int grid = BB * NCGT * NTB;  // 2048 blocks x 256 threads
  ema_bidir_kernel<<<grid, 256, 0, stream>>>(x, alogit4, out);
}

// Round 4
// 50.228 us; speedup vs baseline: 2.5921x; 2.2908x over previous
//
#include <hip/hip_runtime.h>

// TemporalDenoise: bidirectional per-channel EMA, averaged.
// R4: LDS-staged tiles. Each block owns (b, 32-channel slice = 128B/t,
// 256 time steps) + 24-step halo each side, staged once into LDS (38 KB)
// by a streaming coalesced loop. All scan reads (fwd/bwd warm-up + main)
// hit LDS via XOR-swizzled ds_read_b128 (conflict-free). fwd chunk in
// registers; bwd pass fuses the averaged PLAIN store (nontemporal stores
// measured +25% WRITE_SIZE in R3 -> dropped).
// Halo 24: (0.7)^24 ~ 1.9e-4 carry error, far under the 5e-2 threshold.
// Clamped staging indices make t=0 / t=T-1 exact (EMA over repeated x[0]
// stays x[0], matching the reference init).

#define BB 32
#define TT 2048
#define CGALL 128          // f32x4 groups per (b,t) row (512 ch)
#define CGT 8              // f32x4 groups per block = 32 ch = 128B per t
#define NCGT (CGALL / CGT) // 16
#define TB 256             // output time steps per block
#define HALO 24
#define SLOTS (TB + 2 * HALO)  // 304
#define LCH 16                 // time steps per thread
#define NCHB (TB / LCH)        // 16 chunks
#define NTHREADS (NCHB * CGT)  // 128 threads = 2 waves
#define NTB (TT / TB)          // 8 time tiles

typedef float f32x4 __attribute__((ext_vector_type(4)));

static __device__ __forceinline__ void ema4(f32x4& c, const f32x4 v,
                                            const f32x4 a, const f32x4 d) {
  c.x = fmaf(a.x, v.x, d.x * c.x);
  c.y = fmaf(a.y, v.y, d.y * c.y);
  c.z = fmaf(a.z, v.z, d.z * c.z);
  c.w = fmaf(a.w, v.w, d.w * c.w);
}

// swizzled LDS index for (slot s, group g): spreads bank-groups so that
// ds_read_b128 across a wave (cgi x ch) and staging ds_write are conflict-free
static __device__ __forceinline__ int swz(int s, int g) {
  return s * CGT + (g ^ ((s >> 3) & 7));
}

__global__ __launch_bounds__(NTHREADS, 2) void ema_bidir_kernel(
    const f32x4* __restrict__ x, const f32x4* __restrict__ alogit4,
    f32x4* __restrict__ out) {
  __shared__ f32x4 tile[SLOTS * CGT];  // 38912 B

  const int bid = blockIdx.x;
  const int tb = bid & (NTB - 1);           // time tile (fast -> XCD spread)
  const int cgt = (bid >> 3) & (NCGT - 1);  // channel tile
  const int b = bid >> 7;                   // batch

  const int tid = threadIdx.x;
  const int cgi = tid & (CGT - 1);  // 0..7 channel group within tile
  const int ch = tid >> 3;          // 0..15 time chunk within tile

  const int tile_t0 = tb * TB;
  const f32x4* xb = x + ((size_t)b * TT) * CGALL + cgt * CGT;
  f32x4* ob = out + ((size_t)b * TT) * CGALL + cgt * CGT;

  // ---- stage tile (+halo) into LDS: streaming, coalesced, clamped ----
#pragma unroll
  for (int k = 0; k < (SLOTS * CGT) / NTHREADS; ++k) {  // 19 iters
    const int f = tid + k * NTHREADS;
    const int s = f >> 3, gi = f & 7;
    int t = tile_t0 - HALO + s;
    t = t < 0 ? 0 : (t > TT - 1 ? TT - 1 : t);
    tile[swz(s, gi)] = xb[(size_t)t * CGALL + gi];
  }

  const f32x4 al = alogit4[cgt * CGT + cgi];
  f32x4 a, d;
  a.x = 1.0f / (1.0f + __expf(-al.x));
  a.y = 1.0f / (1.0f + __expf(-al.y));
  a.z = 1.0f / (1.0f + __expf(-al.z));
  a.w = 1.0f / (1.0f + __expf(-al.w));
  d = 1.0f - a;

  __syncthreads();

  const int s0 = HALO + ch * LCH;  // first main slot of this chunk

  // ---- warm-ups (fwd and bwd chains are independent -> interleave) ----
  f32x4 cf = tile[swz(s0 - HALO, cgi)];
  f32x4 cb = tile[swz(s0 + LCH - 1 + HALO, cgi)];
#pragma unroll
  for (int k = 1; k < HALO; ++k) {
    ema4(cf, tile[swz(s0 - HALO + k, cgi)], a, d);
    ema4(cb, tile[swz(s0 + LCH - 1 + HALO - k, cgi)], a, d);
  }

  // ---- forward main: record chunk in registers ----
  f32x4 fr[LCH];
#pragma unroll
  for (int i = 0; i < LCH; ++i) {
    ema4(cf, tile[swz(s0 + i, cgi)], a, d);
    fr[i] = cf;
  }

  // ---- backward main, fused averaged store (plain, full-line) ----
#pragma unroll
  for (int i = LCH - 1; i >= 0; --i) {
    ema4(cb, tile[swz(s0 + i, cgi)], a, d);
    f32x4 r;
    r.x = 0.5f * (fr[i].x + cb.x);
    r.y = 0.5f * (fr[i].y + cb.y);
    r.z = 0.5f * (fr[i].z + cb.z);
    r.w = 0.5f * (fr[i].w + cb.w);
    ob[(size_t)(tile_t0 + ch * LCH + i) * CGALL + cgi] = r;
  }
}

extern "C" void kernel_launch(void* const* d_in, const int* in_sizes, int n_in,
                              void* d_out, int out_size, void* d_ws,
                              size_t ws_size, hipStream_t stream) {
  const f32x4* x = (const f32x4*)d_in[0];
  const f32x4* alogit4 = (const f32x4*)d_in[1];
  f32x4* out = (f32x4*)d_out;

  const int grid = BB * NCGT * NTB;  // 4096 blocks x 128 threads
  ema_bidir_kernel<<<grid, NTHREADS, 0, stream>>>(x, alogit4, out);
}